// Round 14
// baseline (262.221 us; speedup 1.0000x reference)
//
#include <hip/hip_runtime.h>
#include <hip/hip_bf16.h>

// GCN layer: h = x@W; symmetric-norm aggregation with self-loops; +b, relu, log_softmax.
// Decomposition: g[i] = (x[i]@W)*dinv[i]; out[c] = LSM(relu(dinv[c]*(g[c]+sum_{e:col=c} g[row_e]) + b))
// R11 measured 249.8us total; aggregate 63us (VALUBusy 50%, 7.4TB/s effective gather BW).
// R12 increments (unmeasured: R12/R13 timeouts; resubmitted byte-identical): 16-deep
//   aggregate ladder (deg~Poisson(16): 54% of nodes get 16 outstanding gathers),
//   int4 bucket_count reads, bin_edges TILE 2048 (2x blocks/CU).

#define IN_CH 128
#define OUT_CH 64
#define NPAD 100352        // N rounded up; workspace stride (>= N+1)
#define BSHIFT 7           // bucket width = 128 nodes
#define BW 128             // nodes per bucket
#define MAXNB 1024         // max buckets
#define TILE 2048          // edges staged per block in bin_edges

// ---------------- bucket histogram: bcount[col>>7]++ (LDS-staged, int4 reads) ----------------
__global__ __launch_bounds__(256) void bucket_count_kernel(
    const int* __restrict__ cols, int* __restrict__ bcount, int E, int NB)
{
    __shared__ int h[MAXNB];
    const int tid = threadIdx.x;
    for (int i = tid; i < NB; i += 256) h[i] = 0;
    __syncthreads();
    const int E4 = E >> 2;
    const int4* c4 = reinterpret_cast<const int4*>(cols);
    for (int i = blockIdx.x * 256 + tid; i < E4; i += gridDim.x * 256) {
        const int4 c = c4[i];
        atomicAdd(&h[c.x >> BSHIFT], 1);
        atomicAdd(&h[c.y >> BSHIFT], 1);
        atomicAdd(&h[c.z >> BSHIFT], 1);
        atomicAdd(&h[c.w >> BSHIFT], 1);
    }
    for (int i = (E4 << 2) + blockIdx.x * 256 + tid; i < E; i += gridDim.x * 256)
        atomicAdd(&h[cols[i] >> BSHIFT], 1);
    __syncthreads();
    for (int i = tid; i < NB; i += 256)
        if (h[i]) atomicAdd(&bcount[i], h[i]);
}

// ---------------- single-block scan over NB buckets -> boffset, bcursor ----------------
__global__ __launch_bounds__(MAXNB) void bucket_scan_kernel(
    const int* __restrict__ bcount, int* __restrict__ boffset,
    int* __restrict__ bcursor, int NB, int E)
{
    __shared__ int sdata[MAXNB];
    const int tid = threadIdx.x;
    const int v = (tid < NB) ? bcount[tid] : 0;
    sdata[tid] = v;
    __syncthreads();
    for (int off = 1; off < MAXNB; off <<= 1) {
        int t = 0;
        if (tid >= off) t = sdata[tid - off];
        __syncthreads();
        sdata[tid] += t;
        __syncthreads();
    }
    if (tid < NB) {
        const int excl = sdata[tid] - v;
        boffset[tid] = excl;
        bcursor[tid] = excl;
    }
    if (tid == 0) boffset[NB] = E;
}

// ---------------- bin edges (tile-staged, reservation atomics) ----------------
// Stage TILE edges in LDS; per-block LDS hist; ONE global reservation atomic per
// (block,bucket); per-edge positions from LDS cursors. binned[p] = row | (col&127)<<20.
__global__ __launch_bounds__(256) void bin_edges_kernel(
    const int* __restrict__ rows, const int* __restrict__ cols,
    int* __restrict__ bcursor, int* __restrict__ binned, int E, int NB)
{
    __shared__ int v[TILE];                  // 8 KB packed edge words
    __shared__ unsigned short bk[TILE];      // 4 KB bucket ids
    __shared__ int hist[MAXNB];              // 4 KB
    __shared__ int cur[MAXNB];               // 4 KB
    const int tid = threadIdx.x;
    const int base = blockIdx.x * TILE;
    const int n = min(TILE, E - base);

    for (int i = tid; i < NB; i += 256) hist[i] = 0;
    __syncthreads();
    for (int j = tid; j < n; j += 256) {
        const int c = cols[base + j];
        const int b = c >> BSHIFT;
        v[j] = rows[base + j] | ((c & (BW - 1)) << 20);
        bk[j] = (unsigned short)b;
        atomicAdd(&hist[b], 1);
    }
    __syncthreads();
    for (int i = tid; i < NB; i += 256)
        cur[i] = hist[i] ? atomicAdd(&bcursor[i], hist[i]) : 0;
    __syncthreads();
    for (int j = tid; j < n; j += 256) {
        const int p = atomicAdd(&cur[bk[j]], 1);
        binned[p] = v[j];
    }
}

// ---------------- per-bucket counting sort -> node-sorted csr_src, rowstart, dinv ----------------
__global__ __launch_bounds__(256) void sort_bucket_kernel(
    const int* __restrict__ binned, const int* __restrict__ boffset,
    int* __restrict__ csr_src, int* __restrict__ rowstart,
    float* __restrict__ dinv, int N, int E, int NB)
{
    __shared__ int hist[BW];
    __shared__ int sc[BW];
    __shared__ int cur[BW];
    const int tid = threadIdx.x;
    const int b = blockIdx.x;
    const int lo = b << BSHIFT;
    const int w = min(BW, N - lo);
    const int s0 = boffset[b], s1 = boffset[b + 1];

    if (tid < BW) hist[tid] = 0;
    __syncthreads();
    for (int e = s0 + tid; e < s1; e += 256)
        atomicAdd(&hist[binned[e] >> 20], 1);
    __syncthreads();
    if (tid < BW) sc[tid] = hist[tid];
    __syncthreads();
    for (int off = 1; off < BW; off <<= 1) {       // Hillis-Steele inclusive scan
        int t = 0;
        if (tid >= off && tid < BW) t = sc[tid - off];
        __syncthreads();
        if (tid >= off && tid < BW) sc[tid] += t;
        __syncthreads();
    }
    if (tid < BW) {
        const int abs0 = s0 + sc[tid] - hist[tid]; // absolute exclusive base
        cur[tid] = abs0;
        if (tid < w) {
            rowstart[lo + tid] = abs0;
            dinv[lo + tid] = rsqrtf((float)hist[tid] + 1.0f);
        }
    }
    if (b == NB - 1 && tid == 0) rowstart[N] = E;
    __syncthreads();
    for (int e = s0 + tid; e < s1; e += 256) {
        const int pv = binned[e];
        const int p = atomicAdd(&cur[pv >> 20], 1);
        csr_src[p] = pv & 0xFFFFF;
    }
}

// ---------------- g = (x @ W) * dinv ----------------
// Barrier-free: each wave independently owns rows (4 waves/block, wave-private LDS slice).
__global__ __launch_bounds__(256) void gemm_scale_kernel(
    const float* __restrict__ x, const float* __restrict__ W,
    const float* __restrict__ dinv, float* __restrict__ g, int N)
{
    __shared__ float xs[4][IN_CH];           // 2 KB, one 512B slice per wave

    const int wave = threadIdx.x >> 6;
    const int lane = threadIdx.x & 63;

    float Wreg[IN_CH];                       // lane's W column, statically indexed
    #pragma unroll
    for (int k = 0; k < IN_CH; ++k) Wreg[k] = W[k * OUT_CH + lane];

    const int wid    = blockIdx.x * 4 + wave;
    const int stride = gridDim.x * 4;

    for (int r = wid; r < N; r += stride) {
        float2 v = *reinterpret_cast<const float2*>(x + (size_t)r * IN_CH + lane * 2);
        xs[wave][lane * 2]     = v.x;
        xs[wave][lane * 2 + 1] = v.y;
        const float4* xv = reinterpret_cast<const float4*>(xs[wave]);
        float sum = 0.f;
        #pragma unroll
        for (int k4 = 0; k4 < IN_CH / 4; ++k4) {
            float4 xk = xv[k4];              // broadcast read (all lanes same addr)
            sum = fmaf(xk.x, Wreg[4 * k4 + 0], sum);
            sum = fmaf(xk.y, Wreg[4 * k4 + 1], sum);
            sum = fmaf(xk.z, Wreg[4 * k4 + 2], sum);
            sum = fmaf(xk.w, Wreg[4 * k4 + 3], sum);
        }
        g[(size_t)r * OUT_CH + lane] = sum * dinv[r];
    }
}

// ---------------- aggregate + finalize (wave per node, register acc) ----------------
// 16/8/4/2/1 gather ladder: up to 16 independent 256B gathers in flight per wave.
__global__ __launch_bounds__(256) void aggregate_kernel(
    const float* __restrict__ g, const int* __restrict__ rowstart,
    const int* __restrict__ csr_src, const float* __restrict__ dinv,
    const float* __restrict__ b, float* __restrict__ out, int N)
{
    const int r = blockIdx.x * 4 + (threadIdx.x >> 6);   // wave-uniform
    if (r >= N) return;
    const int lane = threadIdx.x & 63;

    const int s0 = rowstart[r];
    const int s1 = rowstart[r + 1];

    float acc = g[(size_t)r * OUT_CH + lane];   // self-loop term
    for (int base = s0; base < s1; base += 64) {
        const int cnt = min(64, s1 - base);
        int src = 0;
        if (lane < cnt) src = csr_src[base + lane];
        int k = 0;
        if (cnt >= 16) {                     // 16 gathers in flight
            float a0 = 0.f, a1 = 0.f, a2 = 0.f, a3 = 0.f;
            float a4 = 0.f, a5 = 0.f, a6 = 0.f, a7 = 0.f;
            float a8 = 0.f, a9 = 0.f, aA = 0.f, aB = 0.f;
            float aC = 0.f, aD = 0.f, aE = 0.f, aF = 0.f;
            for (; k + 16 <= cnt; k += 16) {
                const int i0 = __shfl(src, k + 0),  i1 = __shfl(src, k + 1);
                const int i2 = __shfl(src, k + 2),  i3 = __shfl(src, k + 3);
                const int i4 = __shfl(src, k + 4),  i5 = __shfl(src, k + 5);
                const int i6 = __shfl(src, k + 6),  i7 = __shfl(src, k + 7);
                const int i8 = __shfl(src, k + 8),  i9 = __shfl(src, k + 9);
                const int iA = __shfl(src, k + 10), iB = __shfl(src, k + 11);
                const int iC = __shfl(src, k + 12), iD = __shfl(src, k + 13);
                const int iE = __shfl(src, k + 14), iF = __shfl(src, k + 15);
                a0 += g[(size_t)i0 * OUT_CH + lane];
                a1 += g[(size_t)i1 * OUT_CH + lane];
                a2 += g[(size_t)i2 * OUT_CH + lane];
                a3 += g[(size_t)i3 * OUT_CH + lane];
                a4 += g[(size_t)i4 * OUT_CH + lane];
                a5 += g[(size_t)i5 * OUT_CH + lane];
                a6 += g[(size_t)i6 * OUT_CH + lane];
                a7 += g[(size_t)i7 * OUT_CH + lane];
                a8 += g[(size_t)i8 * OUT_CH + lane];
                a9 += g[(size_t)i9 * OUT_CH + lane];
                aA += g[(size_t)iA * OUT_CH + lane];
                aB += g[(size_t)iB * OUT_CH + lane];
                aC += g[(size_t)iC * OUT_CH + lane];
                aD += g[(size_t)iD * OUT_CH + lane];
                aE += g[(size_t)iE * OUT_CH + lane];
                aF += g[(size_t)iF * OUT_CH + lane];
            }
            acc += (((a0 + a1) + (a2 + a3)) + ((a4 + a5) + (a6 + a7)))
                 + (((a8 + a9) + (aA + aB)) + ((aC + aD) + (aE + aF)));
        }
        if (k + 8 <= cnt) {                  // 8 gathers in flight
            const int i0 = __shfl(src, k + 0), i1 = __shfl(src, k + 1);
            const int i2 = __shfl(src, k + 2), i3 = __shfl(src, k + 3);
            const int i4 = __shfl(src, k + 4), i5 = __shfl(src, k + 5);
            const int i6 = __shfl(src, k + 6), i7 = __shfl(src, k + 7);
            float a0 = g[(size_t)i0 * OUT_CH + lane];
            float a1 = g[(size_t)i1 * OUT_CH + lane];
            float a2 = g[(size_t)i2 * OUT_CH + lane];
            float a3 = g[(size_t)i3 * OUT_CH + lane];
            float a4 = g[(size_t)i4 * OUT_CH + lane];
            float a5 = g[(size_t)i5 * OUT_CH + lane];
            float a6 = g[(size_t)i6 * OUT_CH + lane];
            float a7 = g[(size_t)i7 * OUT_CH + lane];
            acc += ((a0 + a1) + (a2 + a3)) + ((a4 + a5) + (a6 + a7));
            k += 8;
        }
        if (k + 4 <= cnt) {
            const int i0 = __shfl(src, k + 0), i1 = __shfl(src, k + 1);
            const int i2 = __shfl(src, k + 2), i3 = __shfl(src, k + 3);
            float a0 = g[(size_t)i0 * OUT_CH + lane];
            float a1 = g[(size_t)i1 * OUT_CH + lane];
            float a2 = g[(size_t)i2 * OUT_CH + lane];
            float a3 = g[(size_t)i3 * OUT_CH + lane];
            acc += (a0 + a1) + (a2 + a3);
            k += 4;
        }
        if (k + 2 <= cnt) {
            const int i0 = __shfl(src, k + 0), i1 = __shfl(src, k + 1);
            float a0 = g[(size_t)i0 * OUT_CH + lane];
            float a1 = g[(size_t)i1 * OUT_CH + lane];
            acc += a0 + a1;
            k += 2;
        }
        if (k < cnt)
            acc += g[(size_t)__shfl(src, k) * OUT_CH + lane];
    }

    float v = acc * dinv[r] + b[lane];
    v = fmaxf(v, 0.0f);

    float m = v;
    #pragma unroll
    for (int off = 32; off > 0; off >>= 1) m = fmaxf(m, __shfl_xor(m, off));
    float ex = expf(v - m);
    float s = ex;
    #pragma unroll
    for (int off = 32; off > 0; off >>= 1) s += __shfl_xor(s, off);

    out[(size_t)r * OUT_CH + lane] = v - m - logf(s);
}

// ============ fallback path (small ws / out-of-range N): float-atomic scatter ============
__global__ void fb_count_kernel(const int* __restrict__ cols, float* __restrict__ deg, int E) {
    int i = blockIdx.x * blockDim.x + threadIdx.x;
    if (i < E) atomicAdd(&deg[cols[i]], 1.0f);
}
__global__ void fb_dinv_kernel(float* __restrict__ deg, int N) {
    int i = blockIdx.x * blockDim.x + threadIdx.x;
    if (i < N) deg[i] = rsqrtf(deg[i] + 1.0f);
}
__global__ __launch_bounds__(256) void fb_gemm_kernel(
    const float* __restrict__ x, const float* __restrict__ W,
    const float* __restrict__ dinv, float* __restrict__ g, float* __restrict__ acc, int N)
{
    __shared__ float xs[4][IN_CH];
    const int wave = threadIdx.x >> 6;
    const int lane = threadIdx.x & 63;
    float Wreg[IN_CH];
    #pragma unroll
    for (int k = 0; k < IN_CH; ++k) Wreg[k] = W[k * OUT_CH + lane];
    const int wid    = blockIdx.x * 4 + wave;
    const int stride = gridDim.x * 4;
    for (int r = wid; r < N; r += stride) {
        float2 v = *reinterpret_cast<const float2*>(x + (size_t)r * IN_CH + lane * 2);
        xs[wave][lane * 2] = v.x; xs[wave][lane * 2 + 1] = v.y;
        const float4* xv = reinterpret_cast<const float4*>(xs[wave]);
        float sum = 0.f;
        #pragma unroll
        for (int k4 = 0; k4 < IN_CH / 4; ++k4) {
            float4 xk = xv[k4];
            sum = fmaf(xk.x, Wreg[4 * k4 + 0], sum);
            sum = fmaf(xk.y, Wreg[4 * k4 + 1], sum);
            sum = fmaf(xk.z, Wreg[4 * k4 + 2], sum);
            sum = fmaf(xk.w, Wreg[4 * k4 + 3], sum);
        }
        const float gv = sum * dinv[r];
        g[(size_t)r * OUT_CH + lane] = gv;
        acc[(size_t)r * OUT_CH + lane] = gv;
    }
}
__global__ __launch_bounds__(256) void fb_scatter_kernel(
    const int* __restrict__ rows, const int* __restrict__ cols,
    const float* __restrict__ g, float* __restrict__ acc, int E)
{
    const int e = blockIdx.x * 4 + (threadIdx.x >> 6);
    if (e >= E) return;
    const int lane = threadIdx.x & 63;
    atomicAdd(&acc[(size_t)cols[e] * OUT_CH + lane], g[(size_t)rows[e] * OUT_CH + lane]);
}
__global__ __launch_bounds__(256) void fb_finalize_kernel(
    float* __restrict__ acc, const float* __restrict__ dinv, const float* __restrict__ b, int N)
{
    const int r = blockIdx.x * 4 + (threadIdx.x >> 6);
    if (r >= N) return;
    const int lane = threadIdx.x & 63;
    float v = acc[(size_t)r * OUT_CH + lane] * dinv[r] + b[lane];
    v = fmaxf(v, 0.0f);
    float m = v;
    #pragma unroll
    for (int off = 32; off > 0; off >>= 1) m = fmaxf(m, __shfl_xor(m, off));
    float ex = expf(v - m);
    float s = ex;
    #pragma unroll
    for (int off = 32; off > 0; off >>= 1) s += __shfl_xor(s, off);
    acc[(size_t)r * OUT_CH + lane] = v - m - logf(s);
}

extern "C" void kernel_launch(void* const* d_in, const int* in_sizes, int n_in,
                              void* d_out, int out_size, void* d_ws, size_t ws_size,
                              hipStream_t stream) {
    const float* x  = (const float*)d_in[0];
    const int*   ei = (const int*)d_in[1];
    const float* W  = (const float*)d_in[2];
    const float* b  = (const float*)d_in[3];
    float* out = (float*)d_out;

    const int N = in_sizes[0] / IN_CH;       // 100000
    const int E = in_sizes[1] / 2;           // 1600000
    const int* rows = ei;                    // edge_index[0] = src
    const int* cols = ei + E;                // edge_index[1] = dst
    const int NB = (N + BW - 1) >> BSHIFT;   // 782 buckets
    const int NT = (E + TILE - 1) / TILE;    // 782 bin tiles

    // workspace layout (4-byte units):
    //   dinv[NPAD] | bcount[2048] | boffset[2048] | bcursor[2048] | rowstart[NPAD] |
    //   csr_src[Epad] | g[N*64]   (binned overlays g: used only before gemm runs)
    const size_t Epad = ((size_t)E + 127) & ~(size_t)127;
    const size_t need = ((size_t)NPAD * 2 + 6144 + Epad + (size_t)N * OUT_CH) * 4;

    if (ws_size >= need && NB <= MAXNB && N < (1 << 20)) {
        float* dinv     = (float*)d_ws;
        int*   bcount   = (int*)d_ws + NPAD;
        int*   boffset  = (int*)d_ws + NPAD + 2048;
        int*   bcursor  = (int*)d_ws + NPAD + 4096;
        int*   rowstart = (int*)d_ws + NPAD + 6144;
        int*   csr_src  = (int*)d_ws + 2 * NPAD + 6144;
        float* g        = (float*)d_ws + 2 * NPAD + 6144 + Epad;
        int*   binned   = (int*)g;           // overlay: dead once gemm writes g

        hipMemsetAsync(bcount, 0, (size_t)NB * sizeof(int), stream);
        bucket_count_kernel<<<256, 256, 0, stream>>>(cols, bcount, E, NB);
        bucket_scan_kernel<<<1, MAXNB, 0, stream>>>(bcount, boffset, bcursor, NB, E);
        bin_edges_kernel<<<NT, 256, 0, stream>>>(rows, cols, bcursor, binned, E, NB);
        sort_bucket_kernel<<<NB, 256, 0, stream>>>(binned, boffset, csr_src, rowstart, dinv, N, E, NB);
        gemm_scale_kernel<<<2048, 256, 0, stream>>>(x, W, dinv, g, N);
        aggregate_kernel<<<(N + 3) / 4, 256, 0, stream>>>(g, rowstart, csr_src, dinv, b, out, N);
    } else {
        // fallback: atomic scatter (needs dinv[NPAD] + g[N*64] floats)
        float* deg = (float*)d_ws;
        float* g   = (float*)d_ws + NPAD;
        hipMemsetAsync(deg, 0, (size_t)N * sizeof(float), stream);
        fb_count_kernel<<<(E + 255) / 256, 256, 0, stream>>>(cols, deg, E);
        fb_dinv_kernel<<<(N + 255) / 256, 256, 0, stream>>>(deg, N);
        fb_gemm_kernel<<<2048, 256, 0, stream>>>(x, W, deg, g, out, N);
        fb_scatter_kernel<<<(E + 3) / 4, 256, 0, stream>>>(rows, cols, g, out, E);
        fb_finalize_kernel<<<(N + 3) / 4, 256, 0, stream>>>(out, deg, b, N);
    }
}

// Round 15
// 249.481 us; speedup vs baseline: 1.0511x; 1.0511x over previous
//
#include <hip/hip_runtime.h>
#include <hip/hip_bf16.h>

// GCN layer: h = x@W; symmetric-norm aggregation with self-loops; +b, relu, log_softmax.
// Decomposition: g[i] = (x[i]@W)*dinv[i]; out[c] = LSM(relu(dinv[c]*(g[c]+sum_{e:col=c} g[row_e]) + b))
// R14 post-mortem: 16-deep ladder null (63->65us, occupancy 72->64%) => aggregate is NOT
//   latency-bound at 8 deep; it's VALU-issue (50% busy: shuffle+addr+load+add per edge) +
//   L2-miss-BW bound. R15: float2 dual-edge gathers (half=lane>>5 picks edge, ch=lane&31
//   holds channel pair) halve per-edge instructions at same bytes/precision; 8-inst ladder
//   still covers 16 edges in flight. Preprocessing reverted to R11 state (TILE 4096,
//   scalar bucket_count) - the R12 tweaks measured ~+10us.

#define IN_CH 128
#define OUT_CH 64
#define NPAD 100352        // N rounded up; workspace stride (>= N+1)
#define BSHIFT 7           // bucket width = 128 nodes
#define BW 128             // nodes per bucket
#define MAXNB 1024         // max buckets
#define TILE 4096          // edges staged per block in bin_edges (R11-measured config)

// ---------------- bucket histogram: bcount[col>>7]++ (LDS-staged) ----------------
__global__ __launch_bounds__(256) void bucket_count_kernel(
    const int* __restrict__ cols, int* __restrict__ bcount, int E, int NB)
{
    __shared__ int h[MAXNB];
    const int tid = threadIdx.x;
    for (int i = tid; i < NB; i += 256) h[i] = 0;
    __syncthreads();
    for (int i = blockIdx.x * 256 + tid; i < E; i += gridDim.x * 256)
        atomicAdd(&h[cols[i] >> BSHIFT], 1);
    __syncthreads();
    for (int i = tid; i < NB; i += 256)
        if (h[i]) atomicAdd(&bcount[i], h[i]);
}

// ---------------- single-block scan over NB buckets -> boffset, bcursor ----------------
__global__ __launch_bounds__(MAXNB) void bucket_scan_kernel(
    const int* __restrict__ bcount, int* __restrict__ boffset,
    int* __restrict__ bcursor, int NB, int E)
{
    __shared__ int sdata[MAXNB];
    const int tid = threadIdx.x;
    const int v = (tid < NB) ? bcount[tid] : 0;
    sdata[tid] = v;
    __syncthreads();
    for (int off = 1; off < MAXNB; off <<= 1) {
        int t = 0;
        if (tid >= off) t = sdata[tid - off];
        __syncthreads();
        sdata[tid] += t;
        __syncthreads();
    }
    if (tid < NB) {
        const int excl = sdata[tid] - v;
        boffset[tid] = excl;
        bcursor[tid] = excl;
    }
    if (tid == 0) boffset[NB] = E;
}

// ---------------- bin edges (tile-staged, reservation atomics) ----------------
__global__ __launch_bounds__(256) void bin_edges_kernel(
    const int* __restrict__ rows, const int* __restrict__ cols,
    int* __restrict__ bcursor, int* __restrict__ binned, int E, int NB)
{
    __shared__ int v[TILE];                  // 16 KB packed edge words
    __shared__ unsigned short bk[TILE];      // 8 KB bucket ids
    __shared__ int hist[MAXNB];              // 4 KB
    __shared__ int cur[MAXNB];               // 4 KB
    const int tid = threadIdx.x;
    const int base = blockIdx.x * TILE;
    const int n = min(TILE, E - base);

    for (int i = tid; i < NB; i += 256) hist[i] = 0;
    __syncthreads();
    for (int j = tid; j < n; j += 256) {
        const int c = cols[base + j];
        const int b = c >> BSHIFT;
        v[j] = rows[base + j] | ((c & (BW - 1)) << 20);
        bk[j] = (unsigned short)b;
        atomicAdd(&hist[b], 1);
    }
    __syncthreads();
    for (int i = tid; i < NB; i += 256)
        cur[i] = hist[i] ? atomicAdd(&bcursor[i], hist[i]) : 0;
    __syncthreads();
    for (int j = tid; j < n; j += 256) {
        const int p = atomicAdd(&cur[bk[j]], 1);
        binned[p] = v[j];
    }
}

// ---------------- per-bucket counting sort -> node-sorted csr_src, rowstart, dinv ----------------
__global__ __launch_bounds__(256) void sort_bucket_kernel(
    const int* __restrict__ binned, const int* __restrict__ boffset,
    int* __restrict__ csr_src, int* __restrict__ rowstart,
    float* __restrict__ dinv, int N, int E, int NB)
{
    __shared__ int hist[BW];
    __shared__ int sc[BW];
    __shared__ int cur[BW];
    const int tid = threadIdx.x;
    const int b = blockIdx.x;
    const int lo = b << BSHIFT;
    const int w = min(BW, N - lo);
    const int s0 = boffset[b], s1 = boffset[b + 1];

    if (tid < BW) hist[tid] = 0;
    __syncthreads();
    for (int e = s0 + tid; e < s1; e += 256)
        atomicAdd(&hist[binned[e] >> 20], 1);
    __syncthreads();
    if (tid < BW) sc[tid] = hist[tid];
    __syncthreads();
    for (int off = 1; off < BW; off <<= 1) {       // Hillis-Steele inclusive scan
        int t = 0;
        if (tid >= off && tid < BW) t = sc[tid - off];
        __syncthreads();
        if (tid >= off && tid < BW) sc[tid] += t;
        __syncthreads();
    }
    if (tid < BW) {
        const int abs0 = s0 + sc[tid] - hist[tid]; // absolute exclusive base
        cur[tid] = abs0;
        if (tid < w) {
            rowstart[lo + tid] = abs0;
            dinv[lo + tid] = rsqrtf((float)hist[tid] + 1.0f);
        }
    }
    if (b == NB - 1 && tid == 0) rowstart[N] = E;
    __syncthreads();
    for (int e = s0 + tid; e < s1; e += 256) {
        const int pv = binned[e];
        const int p = atomicAdd(&cur[pv >> 20], 1);
        csr_src[p] = pv & 0xFFFFF;
    }
}

// ---------------- g = (x @ W) * dinv ----------------
__global__ __launch_bounds__(256) void gemm_scale_kernel(
    const float* __restrict__ x, const float* __restrict__ W,
    const float* __restrict__ dinv, float* __restrict__ g, int N)
{
    __shared__ float xs[4][IN_CH];           // 2 KB, one 512B slice per wave

    const int wave = threadIdx.x >> 6;
    const int lane = threadIdx.x & 63;

    float Wreg[IN_CH];                       // lane's W column, statically indexed
    #pragma unroll
    for (int k = 0; k < IN_CH; ++k) Wreg[k] = W[k * OUT_CH + lane];

    const int wid    = blockIdx.x * 4 + wave;
    const int stride = gridDim.x * 4;

    for (int r = wid; r < N; r += stride) {
        float2 v = *reinterpret_cast<const float2*>(x + (size_t)r * IN_CH + lane * 2);
        xs[wave][lane * 2]     = v.x;
        xs[wave][lane * 2 + 1] = v.y;
        const float4* xv = reinterpret_cast<const float4*>(xs[wave]);
        float sum = 0.f;
        #pragma unroll
        for (int k4 = 0; k4 < IN_CH / 4; ++k4) {
            float4 xk = xv[k4];              // broadcast read (all lanes same addr)
            sum = fmaf(xk.x, Wreg[4 * k4 + 0], sum);
            sum = fmaf(xk.y, Wreg[4 * k4 + 1], sum);
            sum = fmaf(xk.z, Wreg[4 * k4 + 2], sum);
            sum = fmaf(xk.w, Wreg[4 * k4 + 3], sum);
        }
        g[(size_t)r * OUT_CH + lane] = sum * dinv[r];
    }
}

// ---------------- aggregate + finalize (wave per node, float2 dual-edge gathers) ----------------
// half = lane>>5 selects edge within a pair; ch = lane&31 holds channels (2ch, 2ch+1).
// One load instruction fetches TWO edges' rows (2 x 256B). 8-inst ladder = 16 edges in flight.
__global__ __launch_bounds__(256) void aggregate_kernel(
    const float* __restrict__ g, const int* __restrict__ rowstart,
    const int* __restrict__ csr_src, const float* __restrict__ dinv,
    const float* __restrict__ b, float* __restrict__ out, int N)
{
    const int r = blockIdx.x * 4 + (threadIdx.x >> 6);   // wave-uniform
    if (r >= N) return;
    const int lane = threadIdx.x & 63;
    const int half = lane >> 5;              // which edge of the pair
    const int ch   = lane & 31;              // channel-pair index
    const float2* g2 = reinterpret_cast<const float2*>(g);

    const int s0 = rowstart[r];
    const int s1 = rowstart[r + 1];

    float ax = 0.f, ay = 0.f;
    if (half == 0) {                         // self-loop on half 0 only
        const float2 sv = g2[(size_t)r * 32 + ch];
        ax = sv.x; ay = sv.y;
    }

    for (int base = s0; base < s1; base += 64) {
        const int cnt = min(64, s1 - base);
        int src = 0;
        if (lane < cnt) src = csr_src[base + lane];
        int k = 0;
        if (cnt >= 16) {                     // 8 load insts = 16 edges in flight
            float2 a0{0,0}, a1{0,0}, a2{0,0}, a3{0,0};
            float2 a4{0,0}, a5{0,0}, a6{0,0}, a7{0,0};
            for (; k + 16 <= cnt; k += 16) {
                const int i0 = __shfl(src, k + 0  + half);
                const int i1 = __shfl(src, k + 2  + half);
                const int i2 = __shfl(src, k + 4  + half);
                const int i3 = __shfl(src, k + 6  + half);
                const int i4 = __shfl(src, k + 8  + half);
                const int i5 = __shfl(src, k + 10 + half);
                const int i6 = __shfl(src, k + 12 + half);
                const int i7 = __shfl(src, k + 14 + half);
                const float2 v0 = g2[(size_t)i0 * 32 + ch];
                const float2 v1 = g2[(size_t)i1 * 32 + ch];
                const float2 v2 = g2[(size_t)i2 * 32 + ch];
                const float2 v3 = g2[(size_t)i3 * 32 + ch];
                const float2 v4 = g2[(size_t)i4 * 32 + ch];
                const float2 v5 = g2[(size_t)i5 * 32 + ch];
                const float2 v6 = g2[(size_t)i6 * 32 + ch];
                const float2 v7 = g2[(size_t)i7 * 32 + ch];
                a0.x += v0.x; a0.y += v0.y;  a1.x += v1.x; a1.y += v1.y;
                a2.x += v2.x; a2.y += v2.y;  a3.x += v3.x; a3.y += v3.y;
                a4.x += v4.x; a4.y += v4.y;  a5.x += v5.x; a5.y += v5.y;
                a6.x += v6.x; a6.y += v6.y;  a7.x += v7.x; a7.y += v7.y;
            }
            ax += ((a0.x + a1.x) + (a2.x + a3.x)) + ((a4.x + a5.x) + (a6.x + a7.x));
            ay += ((a0.y + a1.y) + (a2.y + a3.y)) + ((a4.y + a5.y) + (a6.y + a7.y));
        }
        if (k + 8 <= cnt) {                  // 4 insts = 8 edges
            const int i0 = __shfl(src, k + 0 + half);
            const int i1 = __shfl(src, k + 2 + half);
            const int i2 = __shfl(src, k + 4 + half);
            const int i3 = __shfl(src, k + 6 + half);
            const float2 v0 = g2[(size_t)i0 * 32 + ch];
            const float2 v1 = g2[(size_t)i1 * 32 + ch];
            const float2 v2 = g2[(size_t)i2 * 32 + ch];
            const float2 v3 = g2[(size_t)i3 * 32 + ch];
            ax += (v0.x + v1.x) + (v2.x + v3.x);
            ay += (v0.y + v1.y) + (v2.y + v3.y);
            k += 8;
        }
        if (k + 4 <= cnt) {                  // 2 insts = 4 edges
            const int i0 = __shfl(src, k + 0 + half);
            const int i1 = __shfl(src, k + 2 + half);
            const float2 v0 = g2[(size_t)i0 * 32 + ch];
            const float2 v1 = g2[(size_t)i1 * 32 + ch];
            ax += v0.x + v1.x;
            ay += v0.y + v1.y;
            k += 4;
        }
        if (k + 2 <= cnt) {                  // 1 inst = 2 edges
            const int i0 = __shfl(src, k + half);
            const float2 v0 = g2[(size_t)i0 * 32 + ch];
            ax += v0.x; ay += v0.y;
            k += 2;
        }
        if (k < cnt) {                       // odd tail: half 0 only
            const int i0 = __shfl(src, k);
            if (half == 0) {
                const float2 v0 = g2[(size_t)i0 * 32 + ch];
                ax += v0.x; ay += v0.y;
            }
        }
    }

    // merge the two halves; afterwards every lane holds the full channel-pair sum
    ax += __shfl_xor(ax, 32);
    ay += __shfl_xor(ay, 32);

    const float di = dinv[r];
    const float2 b2 = *reinterpret_cast<const float2*>(b + ch * 2);
    float vx = fmaxf(ax * di + b2.x, 0.0f);
    float vy = fmaxf(ay * di + b2.y, 0.0f);

    float m = fmaxf(vx, vy);
    #pragma unroll
    for (int off = 16; off > 0; off >>= 1) m = fmaxf(m, __shfl_xor(m, off));
    const float ex = expf(vx - m);
    const float ey = expf(vy - m);
    float s = ex + ey;
    #pragma unroll
    for (int off = 16; off > 0; off >>= 1) s += __shfl_xor(s, off);
    const float ls = logf(s);

    if (half == 0) {
        float2 o;
        o.x = vx - m - ls;
        o.y = vy - m - ls;
        *reinterpret_cast<float2*>(out + (size_t)r * OUT_CH + ch * 2) = o;
    }
}

// ============ fallback path (small ws / out-of-range N): float-atomic scatter ============
__global__ void fb_count_kernel(const int* __restrict__ cols, float* __restrict__ deg, int E) {
    int i = blockIdx.x * blockDim.x + threadIdx.x;
    if (i < E) atomicAdd(&deg[cols[i]], 1.0f);
}
__global__ void fb_dinv_kernel(float* __restrict__ deg, int N) {
    int i = blockIdx.x * blockDim.x + threadIdx.x;
    if (i < N) deg[i] = rsqrtf(deg[i] + 1.0f);
}
__global__ __launch_bounds__(256) void fb_gemm_kernel(
    const float* __restrict__ x, const float* __restrict__ W,
    const float* __restrict__ dinv, float* __restrict__ g, float* __restrict__ acc, int N)
{
    __shared__ float xs[4][IN_CH];
    const int wave = threadIdx.x >> 6;
    const int lane = threadIdx.x & 63;
    float Wreg[IN_CH];
    #pragma unroll
    for (int k = 0; k < IN_CH; ++k) Wreg[k] = W[k * OUT_CH + lane];
    const int wid    = blockIdx.x * 4 + wave;
    const int stride = gridDim.x * 4;
    for (int r = wid; r < N; r += stride) {
        float2 v = *reinterpret_cast<const float2*>(x + (size_t)r * IN_CH + lane * 2);
        xs[wave][lane * 2] = v.x; xs[wave][lane * 2 + 1] = v.y;
        const float4* xv = reinterpret_cast<const float4*>(xs[wave]);
        float sum = 0.f;
        #pragma unroll
        for (int k4 = 0; k4 < IN_CH / 4; ++k4) {
            float4 xk = xv[k4];
            sum = fmaf(xk.x, Wreg[4 * k4 + 0], sum);
            sum = fmaf(xk.y, Wreg[4 * k4 + 1], sum);
            sum = fmaf(xk.z, Wreg[4 * k4 + 2], sum);
            sum = fmaf(xk.w, Wreg[4 * k4 + 3], sum);
        }
        const float gv = sum * dinv[r];
        g[(size_t)r * OUT_CH + lane] = gv;
        acc[(size_t)r * OUT_CH + lane] = gv;
    }
}
__global__ __launch_bounds__(256) void fb_scatter_kernel(
    const int* __restrict__ rows, const int* __restrict__ cols,
    const float* __restrict__ g, float* __restrict__ acc, int E)
{
    const int e = blockIdx.x * 4 + (threadIdx.x >> 6);
    if (e >= E) return;
    const int lane = threadIdx.x & 63;
    atomicAdd(&acc[(size_t)cols[e] * OUT_CH + lane], g[(size_t)rows[e] * OUT_CH + lane]);
}
__global__ __launch_bounds__(256) void fb_finalize_kernel(
    float* __restrict__ acc, const float* __restrict__ dinv, const float* __restrict__ b, int N)
{
    const int r = blockIdx.x * 4 + (threadIdx.x >> 6);
    if (r >= N) return;
    const int lane = threadIdx.x & 63;
    float v = acc[(size_t)r * OUT_CH + lane] * dinv[r] + b[lane];
    v = fmaxf(v, 0.0f);
    float m = v;
    #pragma unroll
    for (int off = 32; off > 0; off >>= 1) m = fmaxf(m, __shfl_xor(m, off));
    float ex = expf(v - m);
    float s = ex;
    #pragma unroll
    for (int off = 32; off > 0; off >>= 1) s += __shfl_xor(s, off);
    acc[(size_t)r * OUT_CH + lane] = v - m - logf(s);
}

extern "C" void kernel_launch(void* const* d_in, const int* in_sizes, int n_in,
                              void* d_out, int out_size, void* d_ws, size_t ws_size,
                              hipStream_t stream) {
    const float* x  = (const float*)d_in[0];
    const int*   ei = (const int*)d_in[1];
    const float* W  = (const float*)d_in[2];
    const float* b  = (const float*)d_in[3];
    float* out = (float*)d_out;

    const int N = in_sizes[0] / IN_CH;       // 100000
    const int E = in_sizes[1] / 2;           // 1600000
    const int* rows = ei;                    // edge_index[0] = src
    const int* cols = ei + E;                // edge_index[1] = dst
    const int NB = (N + BW - 1) >> BSHIFT;   // 782 buckets
    const int NT = (E + TILE - 1) / TILE;    // 391 bin tiles

    // workspace layout (4-byte units):
    //   dinv[NPAD] | bcount[2048] | boffset[2048] | bcursor[2048] | rowstart[NPAD] |
    //   csr_src[Epad] | g[N*64]   (binned overlays g: used only before gemm runs)
    const size_t Epad = ((size_t)E + 127) & ~(size_t)127;
    const size_t need = ((size_t)NPAD * 2 + 6144 + Epad + (size_t)N * OUT_CH) * 4;

    if (ws_size >= need && NB <= MAXNB && N < (1 << 20)) {
        float* dinv     = (float*)d_ws;
        int*   bcount   = (int*)d_ws + NPAD;
        int*   boffset  = (int*)d_ws + NPAD + 2048;
        int*   bcursor  = (int*)d_ws + NPAD + 4096;
        int*   rowstart = (int*)d_ws + NPAD + 6144;
        int*   csr_src  = (int*)d_ws + 2 * NPAD + 6144;
        float* g        = (float*)d_ws + 2 * NPAD + 6144 + Epad;
        int*   binned   = (int*)g;           // overlay: dead once gemm writes g

        hipMemsetAsync(bcount, 0, (size_t)NB * sizeof(int), stream);
        bucket_count_kernel<<<256, 256, 0, stream>>>(cols, bcount, E, NB);
        bucket_scan_kernel<<<1, MAXNB, 0, stream>>>(bcount, boffset, bcursor, NB, E);
        bin_edges_kernel<<<NT, 256, 0, stream>>>(rows, cols, bcursor, binned, E, NB);
        sort_bucket_kernel<<<NB, 256, 0, stream>>>(binned, boffset, csr_src, rowstart, dinv, N, E, NB);
        gemm_scale_kernel<<<2048, 256, 0, stream>>>(x, W, dinv, g, N);
        aggregate_kernel<<<(N + 3) / 4, 256, 0, stream>>>(g, rowstart, csr_src, dinv, b, out, N);
    } else {
        // fallback: atomic scatter (needs dinv[NPAD] + g[N*64] floats)
        float* deg = (float*)d_ws;
        float* g   = (float*)d_ws + NPAD;
        hipMemsetAsync(deg, 0, (size_t)N * sizeof(float), stream);
        fb_count_kernel<<<(E + 255) / 256, 256, 0, stream>>>(cols, deg, E);
        fb_dinv_kernel<<<(N + 255) / 256, 256, 0, stream>>>(deg, N);
        fb_gemm_kernel<<<2048, 256, 0, stream>>>(x, W, deg, g, out, N);
        fb_scatter_kernel<<<(E + 3) / 4, 256, 0, stream>>>(rows, cols, g, out, E);
        fb_finalize_kernel<<<(N + 3) / 4, 256, 0, stream>>>(out, deg, b, N);
    }
}